// Round 1
// baseline (357.521 us; speedup 1.0000x reference)
//
#include <hip/hip_runtime.h>
#include <math.h>

// Problem constants (from reference)
constexpr int B_SZ = 16384;
constexpr int G_SZ = 256;
constexpr long long CELLS = (long long)B_SZ * G_SZ;     // 4,194,304 cells; 2 anchor slots each
constexpr int CLS_CELLS = 16384 / 2;                     // logits[:batch_size] -> first 16384 (cell,slot) rows -> 8192 cells
constexpr float NOOBJ_SCALE = 0.5f;
constexpr float COORD_SCALE = 5.0f;

// Per-(cell,slot) loss contribution.
// pred slot layout: offset=p0, dur=p1, conf=p2, cls=p3..p5  (slot1: +6)
// target slot layout: conf, cls, offset, dur                (slot1: +4)
__device__ __forceinline__ float slot_loss(float pc, float l0, float l1, float l2,
                                           float po, float pd,
                                           float tc, float tcls, float to, float td,
                                           bool do_cls) {
    // conf loss: obj weight 1.0 (tc==1), noobj weight 0.5 (tc==0)
    float d = tc - pc;
    bool obj = (tc == 1.0f);
    float w = obj ? 1.0f : ((tc == 0.0f) ? NOOBJ_SCALE : 0.0f);
    float r = w * d * d;

    if (obj) {
        float doff = to - po;
        r += COORD_SCALE * doff * doff;
        float dd = sqrtf(td) - sqrtf(pd);
        r += COORD_SCALE * dd * dd;
    }
    if (do_cls) {
        // logits = obj ? pred_cls : (0,0,0); idx = obj ? int(gt_cls) : 0
        float x0, x1, x2;
        int idx;
        if (obj) { x0 = l0; x1 = l1; x2 = l2; idx = (int)tcls; }
        else     { x0 = 0.f; x1 = 0.f; x2 = 0.f; idx = 0; }
        float m = fmaxf(x0, fmaxf(x1, x2));
        float lse = logf(expf(x0 - m) + expf(x1 - m) + expf(x2 - m)) + m;
        float li = (idx == 0) ? x0 : ((idx == 1) ? x1 : x2);
        r += lse - li;   // cross-entropy = logsumexp - logit[target]
    }
    return r;
}

__global__ __launch_bounds__(256) void ensemble_loss_kernel(
        const float* __restrict__ pred,
        const float* __restrict__ target,
        double* __restrict__ acc_ws) {
    float acc = 0.0f;
    const long long stride = (long long)gridDim.x * blockDim.x;
    for (long long cell = (long long)blockIdx.x * blockDim.x + threadIdx.x;
         cell < CELLS; cell += stride) {
        const float4* p4 = (const float4*)(pred + cell * 12);
        const float4* t4 = (const float4*)(target + cell * 8);
        float4 a = p4[0];   // p0..p3:  off0, dur0, conf0, cls0_0
        float4 b = p4[1];   // p4..p7:  cls0_1, cls0_2, off1, dur1
        float4 c = p4[2];   // p8..p11: conf1, cls1_0, cls1_1, cls1_2
        float4 t0 = t4[0];  // conf0, cls0, off0, dur0
        float4 t1 = t4[1];  // conf1, cls1, off1, dur1
        bool do_cls = (cell < CLS_CELLS);
        // slot 0
        acc += slot_loss(a.z, a.w, b.x, b.y, a.x, a.y,
                         t0.x, t0.y, t0.z, t0.w, do_cls);
        // slot 1
        acc += slot_loss(c.x, c.y, c.z, c.w, b.z, b.w,
                         t1.x, t1.y, t1.z, t1.w, do_cls);
    }

    // wave(64) shuffle reduction
    for (int off = 32; off > 0; off >>= 1)
        acc += __shfl_down(acc, off, 64);

    __shared__ float wsum[4];  // 256 threads = 4 waves
    int lane = threadIdx.x & 63;
    int wv = threadIdx.x >> 6;
    if (lane == 0) wsum[wv] = acc;
    __syncthreads();
    if (threadIdx.x == 0) {
        float s = wsum[0] + wsum[1] + wsum[2] + wsum[3];
        atomicAdd(acc_ws, (double)s);  // device-scope f64 atomic, one per block
    }
}

__global__ void finalize_kernel(const double* __restrict__ acc_ws,
                                float* __restrict__ out) {
    out[0] = (float)(acc_ws[0] * (1.0 / (double)B_SZ));
}

extern "C" void kernel_launch(void* const* d_in, const int* in_sizes, int n_in,
                              void* d_out, int out_size, void* d_ws, size_t ws_size,
                              hipStream_t stream) {
    const float* pred   = (const float*)d_in[0];
    const float* target = (const float*)d_in[1];
    float* out = (float*)d_out;
    double* acc = (double*)d_ws;

    // d_ws is poisoned 0xAA before every launch — zero the accumulator.
    hipMemsetAsync(d_ws, 0, sizeof(double), stream);

    // 4096 blocks x 256 threads = 1M threads, 4 cells/thread grid-stride.
    ensemble_loss_kernel<<<4096, 256, 0, stream>>>(pred, target, acc);
    finalize_kernel<<<1, 1, 0, stream>>>(acc, out);
}